// Round 4
// baseline (229.310 us; speedup 1.0000x reference)
//
#include <hip/hip_runtime.h>

// VQEmbedding: x [N=32768, D=256] fp32, embedding [M=1024, D=256] fp32.
// Outputs (flat fp32): quantized [N*D], loss [1], indices [N] (as float), perplexity [1].
// Distances via split-fp16 MFMA (hi*hi + hi*lo + lo*hi), exact fp32 enorm,
// loss via identity sum(||x-q||^2) = ||x||_F^2 + sum(enorm[best] - 2*dot_best).
// R2/R3: 32-row tiles (4 blocks/CU), nontemporal x/outQ streams (native vec types)
// so the 1MB split-e tables stay L2-resident.

constexpr int D = 256;
constexpr int M = 1024;
constexpr int ROWS = 32;

typedef _Float16 f16;
typedef __attribute__((ext_vector_type(4))) _Float16 f16x4;
typedef __attribute__((ext_vector_type(8))) _Float16 f16x8;
typedef __attribute__((ext_vector_type(4))) float f32x4;

// ws layout (bytes):
//   [0..4)        loss accumulator (float)
//   [4..4100)     counts (1024 floats, float-idx 1..1025)
//   [4112..8208)  enorm  (1024 floats, float-idx 1028..2052)  (16B aligned)
//   [8320..532608)     eHi (1024*256 f16)
//   [532608..1056896)  eLo (1024*256 f16)
constexpr size_t WS_ENORM_F = 1028;
constexpr size_t WS_EHI_B   = 8320;
constexpr size_t WS_ELO_B   = 532608;
constexpr size_t WS_NEEDED  = 1056896;

// ---------------- prep: split e into f16 hi/lo + exact ||e||^2 ----------------
__global__ void prep_kernel(const float* __restrict__ e, float* __restrict__ ws) {
    int m = blockIdx.x, l = threadIdx.x;   // 64 threads, one float4 each
    f32x4 v = *reinterpret_cast<const f32x4*>(e + m * D + l * 4);
    f16 h0 = (f16)v.x, h1 = (f16)v.y, h2 = (f16)v.z, h3 = (f16)v.w;
    f16x4 hv = {h0, h1, h2, h3};
    f16x4 lv = {(f16)(v.x - (float)h0), (f16)(v.y - (float)h1),
                (f16)(v.z - (float)h2), (f16)(v.w - (float)h3)};
    f16* eHi = reinterpret_cast<f16*>((char*)ws + WS_EHI_B);
    f16* eLo = reinterpret_cast<f16*>((char*)ws + WS_ELO_B);
    *reinterpret_cast<f16x4*>(eHi + m * D + l * 4) = hv;
    *reinterpret_cast<f16x4*>(eLo + m * D + l * 4) = lv;
    float s = fmaf(v.x, v.x, fmaf(v.y, v.y, fmaf(v.z, v.z, v.w * v.w)));
#pragma unroll
    for (int o = 32; o > 0; o >>= 1) s += __shfl_down(s, o, 64);
    if (l == 0) ws[WS_ENORM_F + m] = s;
}

// ---------------- main MFMA kernel ----------------
__global__ __launch_bounds__(256, 4) void vq_mfma_kernel(
    const float* __restrict__ x, const float* __restrict__ e,
    float* __restrict__ outQ, float* __restrict__ outIdx, float* __restrict__ ws)
{
    __shared__ ushort xHi[ROWS * D];   // 16 KB, XOR-swizzled by ((row&7)<<4) on byte addr
    __shared__ ushort xLo[ROWS * D];   // 16 KB
    __shared__ float  enorm_s[M];      // 4 KB
    __shared__ float  wval[4][ROWS];
    __shared__ int    widx[4][ROWS];
    __shared__ int    fidx[ROWS];

    const int tid  = threadIdx.x;
    const int row0 = blockIdx.x * ROWS;

    // enorm -> LDS (1024 floats, one float4/thread)
    {
        f32x4 v = *reinterpret_cast<const f32x4*>(ws + WS_ENORM_F + tid * 4);
        *reinterpret_cast<f32x4*>(&enorm_s[tid * 4]) = v;
    }

    // stage x tile (nontemporal: don't pollute L2 - e tables must stay resident);
    // fp32 -> f16 hi/lo into swizzled LDS; accumulate ||x||_F^2 exactly
    float sxx = 0.f;
#pragma unroll
    for (int it = 0; it < 8; ++it) {
        int f  = it * 256 + tid;        // 2048 float4s per tile
        int rr = f >> 6, c4 = f & 63;
        f32x4 v = __builtin_nontemporal_load(
            reinterpret_cast<const f32x4*>(x + (row0 + rr) * D + c4 * 4));
        sxx += fmaf(v.x, v.x, fmaf(v.y, v.y, fmaf(v.z, v.z, v.w * v.w)));
        f16 h0 = (f16)v.x, h1 = (f16)v.y, h2 = (f16)v.z, h3 = (f16)v.w;
        f16x4 hv = {h0, h1, h2, h3};
        f16x4 lv = {(f16)(v.x - (float)h0), (f16)(v.y - (float)h1),
                    (f16)(v.z - (float)h2), (f16)(v.w - (float)h3)};
        int byte = (rr * 512 + c4 * 8) ^ ((rr & 7) << 4);
        *reinterpret_cast<f16x4*>((char*)xHi + byte) = hv;
        *reinterpret_cast<f16x4*>((char*)xLo + byte) = lv;
    }
#pragma unroll
    for (int o = 32; o > 0; o >>= 1) sxx += __shfl_down(sxx, o, 64);
    if ((tid & 63) == 0) atomicAdd(ws, sxx);
    __syncthreads();

    const int l  = tid & 63;
    const int w  = __builtin_amdgcn_readfirstlane(tid >> 6);  // wave id (SGPR)
    const int lr = l & 15;      // A-row / B-col within frag
    const int q  = l >> 4;      // k-group
    const int aswz = (lr & 7) << 4;
    const f16* eHi = reinterpret_cast<const f16*>((const char*)ws + WS_EHI_B);
    const f16* eLo = reinterpret_cast<const f16*>((const char*)ws + WS_ELO_B);

    float bestV[8];
    int   bestI[8];
#pragma unroll
    for (int s = 0; s < 8; ++s) { bestV[s] = 3.4e38f; bestI[s] = 0; }

    for (int chunk = 0; chunk < 4; ++chunk) {
        const int m0 = w * 256 + chunk * 64;   // wave w owns cols [w*256, w*256+256)
        f32x4 acc[2][4];
#pragma unroll
        for (int rf = 0; rf < 2; ++rf)
#pragma unroll
            for (int cf = 0; cf < 4; ++cf) acc[rf][cf] = (f32x4){0.f, 0.f, 0.f, 0.f};

#pragma unroll
        for (int kk = 0; kk < 8; ++kk) {
            f16x8 ah[2], al[2], bh[4], bl[4];
#pragma unroll
            for (int rf = 0; rf < 2; ++rf) {
                int byte = (((rf * 16 + lr) * 512) + kk * 64 + q * 16) ^ aswz;
                ah[rf] = *reinterpret_cast<const f16x8*>((const char*)xHi + byte);
                al[rf] = *reinterpret_cast<const f16x8*>((const char*)xLo + byte);
            }
#pragma unroll
            for (int cf = 0; cf < 4; ++cf) {
                int eidx = (m0 + cf * 16 + lr) * D + kk * 32 + q * 8;
                bh[cf] = *reinterpret_cast<const f16x8*>(eHi + eidx);
                bl[cf] = *reinterpret_cast<const f16x8*>(eLo + eidx);
            }
#pragma unroll
            for (int rf = 0; rf < 2; ++rf)
#pragma unroll
                for (int cf = 0; cf < 4; ++cf) {
                    acc[rf][cf] = __builtin_amdgcn_mfma_f32_16x16x32_f16(ah[rf], bh[cf], acc[rf][cf], 0, 0, 0);
                    acc[rf][cf] = __builtin_amdgcn_mfma_f32_16x16x32_f16(ah[rf], bl[cf], acc[rf][cf], 0, 0, 0);
                    acc[rf][cf] = __builtin_amdgcn_mfma_f32_16x16x32_f16(al[rf], bh[cf], acc[rf][cf], 0, 0, 0);
                }
        }
        // fold distances into running per-lane argmin (m ascending -> strict < = first min)
#pragma unroll
        for (int cf = 0; cf < 4; ++cf) {
            float en = enorm_s[m0 + cf * 16 + lr];
            int   mi = m0 + cf * 16 + lr;
#pragma unroll
            for (int rf = 0; rf < 2; ++rf)
#pragma unroll
                for (int i = 0; i < 4; ++i) {
                    float dv = fmaf(-2.f, acc[rf][cf][i], en);
                    int s = rf * 4 + i;
                    if (dv < bestV[s]) { bestV[s] = dv; bestI[s] = mi; }
                }
        }
    }

    // reduce across the 16 lanes sharing each row (xor within l&15), tie -> lower idx
#pragma unroll
    for (int s = 0; s < 8; ++s) {
        float v = bestV[s]; int ix = bestI[s];
#pragma unroll
        for (int mk = 1; mk < 16; mk <<= 1) {
            float ov = __shfl_xor(v, mk, 64);
            int   oi = __shfl_xor(ix, mk, 64);
            if (ov < v || (ov == v && oi < ix)) { v = ov; ix = oi; }
        }
        bestV[s] = v; bestI[s] = ix;
    }
    if (lr == 0) {
#pragma unroll
        for (int s = 0; s < 8; ++s) {
            int row = (s >> 2) * 16 + q * 4 + (s & 3);   // rf*16 + q*4 + i
            wval[w][row] = bestV[s];
            widx[w][row] = bestI[s];
        }
    }
    __syncthreads();

    // wave 0, lanes 0..31: combine the 4 waves' column ranges
    if (tid < 32) {
        int r = tid;
        float bv = wval[0][r]; int bi = widx[0][r];
#pragma unroll
        for (int ww = 1; ww < 4; ++ww) {
            float v = wval[ww][r]; int i2 = widx[ww][r];
            if (v < bv || (v == bv && i2 < bi)) { bv = v; bi = i2; }
        }
        fidx[r] = bi;
        outIdx[row0 + r] = (float)bi;
        atomicAdd(ws + 1 + bi, 1.0f);
        float dsum = bv;
#pragma unroll
        for (int o = 16; o > 0; o >>= 1) dsum += __shfl_down(dsum, o, 64);
        if (r == 0) atomicAdd(ws, dsum);
    }
    __syncthreads();

    // gather quantized = embedding[idx] (exact fp32), nontemporal store
#pragma unroll
    for (int it = 0; it < 8; ++it) {
        int f  = it * 256 + tid;
        int rr = f >> 6, c4 = f & 63;
        int idx = fidx[rr];
        f32x4 v = *reinterpret_cast<const f32x4*>(e + idx * D + c4 * 4);
        __builtin_nontemporal_store(v, reinterpret_cast<f32x4*>(outQ + (row0 + rr) * D + c4 * 4));
    }
}

// ---------------- fallback fp32 kernels (used only if ws too small) ----------------
__global__ void enorm_kernel(const float* __restrict__ e, float* __restrict__ enorm) {
    int m = blockIdx.x;
    int l = threadIdx.x;
    const f32x4 v = *reinterpret_cast<const f32x4*>(e + m * D + l * 4);
    float s = fmaf(v.x, v.x, fmaf(v.y, v.y, fmaf(v.z, v.z, v.w * v.w)));
#pragma unroll
    for (int o = 32; o > 0; o >>= 1) s += __shfl_down(s, o, 64);
    if (l == 0) enorm[m] = s;
}

__global__ __launch_bounds__(256, 2) void vq_main_kernel(
    const float* __restrict__ x, const float* __restrict__ e,
    float* __restrict__ outQ, float* __restrict__ outIdx,
    float* __restrict__ ws) {
    __shared__ f32x4 xs[64][64];
    __shared__ float cval[4][64];
    __shared__ int   cidx[4][64];
    __shared__ int   fidx[64];

    const int tid  = threadIdx.x;
    const int row0 = blockIdx.x * 64;

#pragma unroll
    for (int it = 0; it < 16; ++it) {
        int f  = it * 256 + tid;
        int rr = f >> 6, c4 = f & 63;
        f32x4 v = *reinterpret_cast<const f32x4*>(x + (row0 + rr) * D + c4 * 4);
        xs[rr][c4 ^ (rr & 7)] = v;
    }
    __syncthreads();

    const int r  = tid & 63;
    const int c  = __builtin_amdgcn_readfirstlane(tid >> 6);
    const int sw = r & 7;

    float xnorm = 0.f;
    if (c == 0) {
        f32x4 a = (f32x4){0.f, 0.f, 0.f, 0.f};
        for (int d4 = 0; d4 < 64; ++d4) {
            f32x4 xv = xs[r][d4 ^ sw];
            a.x = fmaf(xv.x, xv.x, a.x);
            a.y = fmaf(xv.y, xv.y, a.y);
            a.z = fmaf(xv.z, xv.z, a.z);
            a.w = fmaf(xv.w, xv.w, a.w);
        }
        xnorm = (a.x + a.y) + (a.z + a.w);
    }

    const float* __restrict__ enorm = ws + WS_ENORM_F;

    float bestVal = 3.4e38f;
    int   bestIdx = 0;
    for (int chunk = 0; chunk < M / 32; ++chunk) {
        const int m0 = chunk * 32 + c * 8;
        f32x4 acc[8];
#pragma unroll
        for (int mi = 0; mi < 8; ++mi) acc[mi] = (f32x4){0.f, 0.f, 0.f, 0.f};
#pragma unroll 2
        for (int d4 = 0; d4 < 64; ++d4) {
            const f32x4 xv = xs[r][d4 ^ sw];
#pragma unroll
            for (int mi = 0; mi < 8; ++mi) {
                const f32x4 ev = *reinterpret_cast<const f32x4*>(e + (m0 + mi) * D + d4 * 4);
                acc[mi].x = fmaf(xv.x, ev.x, acc[mi].x);
                acc[mi].y = fmaf(xv.y, ev.y, acc[mi].y);
                acc[mi].z = fmaf(xv.z, ev.z, acc[mi].z);
                acc[mi].w = fmaf(xv.w, ev.w, acc[mi].w);
            }
        }
#pragma unroll
        for (int mi = 0; mi < 8; ++mi) {
            float dot = (acc[mi].x + acc[mi].y) + (acc[mi].z + acc[mi].w);
            float val = enorm[m0 + mi] - 2.0f * dot;
            if (val < bestVal) { bestVal = val; bestIdx = m0 + mi; }
        }
    }
    cval[c][r] = bestVal;
    cidx[c][r] = bestIdx;
    __syncthreads();

    if (c == 0) {
        float bv = bestVal; int bi = bestIdx;
#pragma unroll
        for (int cc = 1; cc < 4; ++cc) {
            float v = cval[cc][r]; int i = cidx[cc][r];
            if (v < bv || (v == bv && i < bi)) { bv = v; bi = i; }
        }
        fidx[r] = bi;
        outIdx[row0 + r] = (float)bi;
        atomicAdd(ws + 1 + bi, 1.0f);
        float dist = bv + xnorm;
#pragma unroll
        for (int o = 32; o > 0; o >>= 1) dist += __shfl_down(dist, o, 64);
        if (r == 0) atomicAdd(ws, dist);
    }
    __syncthreads();

#pragma unroll
    for (int it = 0; it < 16; ++it) {
        int f  = it * 256 + tid;
        int rr = f >> 6, c4 = f & 63;
        int idx = fidx[rr];
        f32x4 v = *reinterpret_cast<const f32x4*>(e + idx * D + c4 * 4);
        *reinterpret_cast<f32x4*>(outQ + (row0 + rr) * D + c4 * 4) = v;
    }
}

// ---------------- finalize: loss + perplexity ----------------
__global__ void vq_final_kernel(const float* __restrict__ ws,
                                float* __restrict__ outLoss, float* __restrict__ outPpl,
                                float invN, float invND) {
    int t = threadIdx.x;  // 1024 threads, one bin each
    float p = ws[1 + t] * invN;
    float term = p * logf(p + 1e-10f);
#pragma unroll
    for (int o = 32; o > 0; o >>= 1) term += __shfl_down(term, o, 64);
    __shared__ float s[16];
    if ((t & 63) == 0) s[t >> 6] = term;
    __syncthreads();
    if (t == 0) {
        float tot = 0.f;
#pragma unroll
        for (int i = 0; i < 16; ++i) tot += s[i];
        *outPpl  = expf(-tot);
        *outLoss = 1.25f * ws[0] * invND;
    }
}

extern "C" void kernel_launch(void* const* d_in, const int* in_sizes, int n_in,
                              void* d_out, int out_size, void* d_ws, size_t ws_size,
                              hipStream_t stream) {
    const float* x = (const float*)d_in[0];
    const float* e = (const float*)d_in[1];
    const int NX = in_sizes[0];     // N*D = 8388608
    const int N  = NX / D;          // 32768

    float* out     = (float*)d_out;
    float* outQ    = out;
    float* outLoss = out + NX;
    float* outIdx  = out + NX + 1;
    float* outPpl  = out + NX + 1 + N;
    float* ws      = (float*)d_ws;

    (void)hipMemsetAsync(d_ws, 0, (1 + M) * sizeof(float), stream);
    if (ws_size >= WS_NEEDED) {
        prep_kernel<<<M, 64, 0, stream>>>(e, ws);
        vq_mfma_kernel<<<N / ROWS, 256, 0, stream>>>(x, e, outQ, outIdx, ws);
    } else {
        enorm_kernel<<<M, 64, 0, stream>>>(e, ws + WS_ENORM_F);
        vq_main_kernel<<<N / 64, 256, 0, stream>>>(x, e, outQ, outIdx, ws);
    }
    vq_final_kernel<<<1, 1024, 0, stream>>>(ws, outLoss, outPpl,
                                            1.0f / (float)N, 1.0f / (float)NX);
}

// Round 5
// 156.627 us; speedup vs baseline: 1.4641x; 1.4641x over previous
//
#include <hip/hip_runtime.h>

// VQEmbedding: x [N=32768, D=256] fp32, embedding [M=1024, D=256] fp32.
// Outputs (flat fp32): quantized [N*D], loss [1], indices [N] (as float), perplexity [1].
// Distances via split-fp16 MFMA (hi*hi + hi*lo + lo*hi), exact fp32 enorm,
// loss via identity sum(||x-q||^2) = ||x||_F^2 + sum(enorm[best] - 2*dot_best).
// R5: e is the MFMA A-operand -> accumulator rows = embeddings -> argmin folds
// in-register (4 (val,idx)/lane, not 64 VGPRs). Freed regs fund a 2-deep
// double-buffered e-prefetch. ROWS=64, 2 blocks/CU, VGPR cap 256.

constexpr int D = 256;
constexpr int M = 1024;
constexpr int ROWS = 64;

typedef _Float16 f16;
typedef __attribute__((ext_vector_type(4))) _Float16 f16x4;
typedef __attribute__((ext_vector_type(8))) _Float16 f16x8;
typedef __attribute__((ext_vector_type(4))) float f32x4;

// ws layout (bytes):
//   [0..4)        loss accumulator (float)
//   [4..4100)     counts (1024 floats, float-idx 1..1025)
//   [4112..8208)  enorm  (1024 floats, float-idx 1028..2052)  (16B aligned)
//   [8320..532608)     eHi (1024*256 f16)
//   [532608..1056896)  eLo (1024*256 f16)
constexpr size_t WS_ENORM_F = 1028;
constexpr size_t WS_EHI_B   = 8320;
constexpr size_t WS_ELO_B   = 532608;
constexpr size_t WS_NEEDED  = 1056896;

// ---------------- prep: split e into f16 hi/lo + exact ||e||^2 ----------------
__global__ void prep_kernel(const float* __restrict__ e, float* __restrict__ ws) {
    int m = blockIdx.x, l = threadIdx.x;   // 64 threads, one float4 each
    f32x4 v = *reinterpret_cast<const f32x4*>(e + m * D + l * 4);
    f16 h0 = (f16)v.x, h1 = (f16)v.y, h2 = (f16)v.z, h3 = (f16)v.w;
    f16x4 hv = {h0, h1, h2, h3};
    f16x4 lv = {(f16)(v.x - (float)h0), (f16)(v.y - (float)h1),
                (f16)(v.z - (float)h2), (f16)(v.w - (float)h3)};
    f16* eHi = reinterpret_cast<f16*>((char*)ws + WS_EHI_B);
    f16* eLo = reinterpret_cast<f16*>((char*)ws + WS_ELO_B);
    *reinterpret_cast<f16x4*>(eHi + m * D + l * 4) = hv;
    *reinterpret_cast<f16x4*>(eLo + m * D + l * 4) = lv;
    float s = fmaf(v.x, v.x, fmaf(v.y, v.y, fmaf(v.z, v.z, v.w * v.w)));
#pragma unroll
    for (int o = 32; o > 0; o >>= 1) s += __shfl_down(s, o, 64);
    if (l == 0) ws[WS_ENORM_F + m] = s;
}

// ---------------- main MFMA kernel (e = A operand, x = B operand) ----------------
__global__ __launch_bounds__(256, 2) void vq_mfma_kernel(
    const float* __restrict__ x, const float* __restrict__ e,
    float* __restrict__ outQ, float* __restrict__ outIdx, float* __restrict__ ws)
{
    __shared__ ushort xHi[ROWS * D];   // 32 KB, XOR-swizzled by ((row&7)<<4) on byte addr
    __shared__ ushort xLo[ROWS * D];   // 32 KB
    __shared__ float  enorm_s[M];      // 4 KB
    __shared__ float  wval[4][ROWS];
    __shared__ int    widx[4][ROWS];
    __shared__ int    fidx[ROWS];

    const int tid  = threadIdx.x;
    const int row0 = blockIdx.x * ROWS;

    // enorm -> LDS (1024 floats, one float4/thread)
    {
        f32x4 v = *reinterpret_cast<const f32x4*>(ws + WS_ENORM_F + tid * 4);
        *reinterpret_cast<f32x4*>(&enorm_s[tid * 4]) = v;
    }

    // stage x tile (nontemporal: keep e L2-resident); fp32 -> f16 hi/lo into
    // swizzled LDS; accumulate ||x||_F^2 exactly
    float sxx = 0.f;
#pragma unroll
    for (int it = 0; it < 16; ++it) {
        int f  = it * 256 + tid;        // 4096 float4s per tile
        int rr = f >> 6, c4 = f & 63;
        f32x4 v = __builtin_nontemporal_load(
            reinterpret_cast<const f32x4*>(x + (row0 + rr) * D + c4 * 4));
        sxx += fmaf(v.x, v.x, fmaf(v.y, v.y, fmaf(v.z, v.z, v.w * v.w)));
        f16 h0 = (f16)v.x, h1 = (f16)v.y, h2 = (f16)v.z, h3 = (f16)v.w;
        f16x4 hv = {h0, h1, h2, h3};
        f16x4 lv = {(f16)(v.x - (float)h0), (f16)(v.y - (float)h1),
                    (f16)(v.z - (float)h2), (f16)(v.w - (float)h3)};
        int byte = (rr * 512 + c4 * 8) ^ ((rr & 7) << 4);
        *reinterpret_cast<f16x4*>((char*)xHi + byte) = hv;
        *reinterpret_cast<f16x4*>((char*)xLo + byte) = lv;
    }
#pragma unroll
    for (int o = 32; o > 0; o >>= 1) sxx += __shfl_down(sxx, o, 64);
    if ((tid & 63) == 0) atomicAdd(ws, sxx);
    __syncthreads();

    const int l  = tid & 63;
    const int w  = __builtin_amdgcn_readfirstlane(tid >> 6);  // wave id (SGPR)
    const int lr = l & 15;      // A-row (emb) / B-col (x-row) within frag
    const int q  = l >> 4;      // k-group
    const int bswz = (lr & 7) << 4;
    const f16* eHi = reinterpret_cast<const f16*>((const char*)ws + WS_EHI_B);
    const f16* eLo = reinterpret_cast<const f16*>((const char*)ws + WS_ELO_B);

    // per-lane running argmin: one (val,idx) per cf (x-row fragment)
    float bestV[4];
    int   bestI[4];
#pragma unroll
    for (int cf = 0; cf < 4; ++cf) { bestV[cf] = 3.4e38f; bestI[cf] = 0; }

    for (int et = 0; et < 4; ++et) {           // wave w owns embs [w*256, w*256+256)
        const int m0 = w * 256 + et * 64;      // this subtile: 64 embeddings
        f32x4 acc[4][4];                       // [rf(emb)][cf(xrow)]
#pragma unroll
        for (int rf = 0; rf < 4; ++rf)
#pragma unroll
            for (int cf = 0; cf < 4; ++cf) acc[rf][cf] = (f32x4){0.f, 0.f, 0.f, 0.f};

        f16x8 Ah[2][4], Al[2][4];              // double-buffered e-fragments
#pragma unroll
        for (int rf = 0; rf < 4; ++rf) {       // prefetch kk=0
            int eidx = (m0 + rf * 16 + lr) * D + q * 8;
            Ah[0][rf] = *reinterpret_cast<const f16x8*>(eHi + eidx);
            Al[0][rf] = *reinterpret_cast<const f16x8*>(eLo + eidx);
        }

#pragma unroll
        for (int kk = 0; kk < 8; ++kk) {
            const int cur = kk & 1, nxt = cur ^ 1;
            if (kk < 7) {
#pragma unroll
                for (int rf = 0; rf < 4; ++rf) {   // prefetch kk+1 while computing kk
                    int eidx = (m0 + rf * 16 + lr) * D + (kk + 1) * 32 + q * 8;
                    Ah[nxt][rf] = *reinterpret_cast<const f16x8*>(eHi + eidx);
                    Al[nxt][rf] = *reinterpret_cast<const f16x8*>(eLo + eidx);
                }
            }
            f16x8 Bh[4], Bl[4];
#pragma unroll
            for (int cf = 0; cf < 4; ++cf) {       // x-fragments from swizzled LDS
                int byte = ((cf * 16 + lr) * 512 + kk * 64 + q * 16) ^ bswz;
                Bh[cf] = *reinterpret_cast<const f16x8*>((const char*)xHi + byte);
                Bl[cf] = *reinterpret_cast<const f16x8*>((const char*)xLo + byte);
            }
#pragma unroll
            for (int rf = 0; rf < 4; ++rf)
#pragma unroll
                for (int cf = 0; cf < 4; ++cf) {
                    acc[rf][cf] = __builtin_amdgcn_mfma_f32_16x16x32_f16(Ah[cur][rf], Bh[cf], acc[rf][cf], 0, 0, 0);
                    acc[rf][cf] = __builtin_amdgcn_mfma_f32_16x16x32_f16(Ah[cur][rf], Bl[cf], acc[rf][cf], 0, 0, 0);
                    acc[rf][cf] = __builtin_amdgcn_mfma_f32_16x16x32_f16(Al[cur][rf], Bh[cf], acc[rf][cf], 0, 0, 0);
                }
        }
        // fold: acc[rf][cf][i] = dot(e[m0+rf*16+q*4+i], x[row0+cf*16+lr])
        // emb index ascends with (et, rf, i) -> strict < keeps first (lowest) min
#pragma unroll
        for (int rf = 0; rf < 4; ++rf)
#pragma unroll
            for (int i = 0; i < 4; ++i) {
                int   mi = m0 + rf * 16 + q * 4 + i;
                float en = enorm_s[mi];
#pragma unroll
                for (int cf = 0; cf < 4; ++cf) {
                    float dv = fmaf(-2.f, acc[rf][cf][i], en);
                    if (dv < bestV[cf]) { bestV[cf] = dv; bestI[cf] = mi; }
                }
            }
    }

    // reduce across the 4 q-groups (lanes sharing the same x-col), tie -> lower idx
#pragma unroll
    for (int cf = 0; cf < 4; ++cf) {
        float v = bestV[cf]; int ix = bestI[cf];
#pragma unroll
        for (int mk = 16; mk < 64; mk <<= 1) {
            float ov = __shfl_xor(v, mk, 64);
            int   oi = __shfl_xor(ix, mk, 64);
            if (ov < v || (ov == v && oi < ix)) { v = ov; ix = oi; }
        }
        bestV[cf] = v; bestI[cf] = ix;
    }
    if (q == 0) {
#pragma unroll
        for (int cf = 0; cf < 4; ++cf) {
            wval[w][cf * 16 + lr] = bestV[cf];
            widx[w][cf * 16 + lr] = bestI[cf];
        }
    }
    __syncthreads();

    // wave 0: combine the 4 waves' emb ranges (ascending w = ascending m)
    if (tid < 64) {
        int r = tid;
        float bv = wval[0][r]; int bi = widx[0][r];
#pragma unroll
        for (int ww = 1; ww < 4; ++ww) {
            float v = wval[ww][r]; int i2 = widx[ww][r];
            if (v < bv || (v == bv && i2 < bi)) { bv = v; bi = i2; }
        }
        fidx[r] = bi;
        outIdx[row0 + r] = (float)bi;
        atomicAdd(ws + 1 + bi, 1.0f);
        float dsum = bv;
#pragma unroll
        for (int o = 32; o > 0; o >>= 1) dsum += __shfl_down(dsum, o, 64);
        if (r == 0) atomicAdd(ws, dsum);
    }
    __syncthreads();

    // gather quantized = embedding[idx] (exact fp32), nontemporal store
#pragma unroll
    for (int it = 0; it < 16; ++it) {
        int f  = it * 256 + tid;
        int rr = f >> 6, c4 = f & 63;
        int idx = fidx[rr];
        f32x4 v = *reinterpret_cast<const f32x4*>(e + idx * D + c4 * 4);
        __builtin_nontemporal_store(v, reinterpret_cast<f32x4*>(outQ + (row0 + rr) * D + c4 * 4));
    }
}

// ---------------- fallback fp32 kernels (used only if ws too small) ----------------
__global__ void enorm_kernel(const float* __restrict__ e, float* __restrict__ enorm) {
    int m = blockIdx.x;
    int l = threadIdx.x;
    const f32x4 v = *reinterpret_cast<const f32x4*>(e + m * D + l * 4);
    float s = fmaf(v.x, v.x, fmaf(v.y, v.y, fmaf(v.z, v.z, v.w * v.w)));
#pragma unroll
    for (int o = 32; o > 0; o >>= 1) s += __shfl_down(s, o, 64);
    if (l == 0) enorm[m] = s;
}

__global__ __launch_bounds__(256, 2) void vq_main_kernel(
    const float* __restrict__ x, const float* __restrict__ e,
    float* __restrict__ outQ, float* __restrict__ outIdx,
    float* __restrict__ ws) {
    __shared__ f32x4 xs[64][64];
    __shared__ float cval[4][64];
    __shared__ int   cidx[4][64];
    __shared__ int   fidx[64];

    const int tid  = threadIdx.x;
    const int row0 = blockIdx.x * 64;

#pragma unroll
    for (int it = 0; it < 16; ++it) {
        int f  = it * 256 + tid;
        int rr = f >> 6, c4 = f & 63;
        f32x4 v = *reinterpret_cast<const f32x4*>(x + (row0 + rr) * D + c4 * 4);
        xs[rr][c4 ^ (rr & 7)] = v;
    }
    __syncthreads();

    const int r  = tid & 63;
    const int c  = __builtin_amdgcn_readfirstlane(tid >> 6);
    const int sw = r & 7;

    float xnorm = 0.f;
    if (c == 0) {
        f32x4 a = (f32x4){0.f, 0.f, 0.f, 0.f};
        for (int d4 = 0; d4 < 64; ++d4) {
            f32x4 xv = xs[r][d4 ^ sw];
            a.x = fmaf(xv.x, xv.x, a.x);
            a.y = fmaf(xv.y, xv.y, a.y);
            a.z = fmaf(xv.z, xv.z, a.z);
            a.w = fmaf(xv.w, xv.w, a.w);
        }
        xnorm = (a.x + a.y) + (a.z + a.w);
    }

    const float* __restrict__ enorm = ws + WS_ENORM_F;

    float bestVal = 3.4e38f;
    int   bestIdx = 0;
    for (int chunk = 0; chunk < M / 32; ++chunk) {
        const int m0 = chunk * 32 + c * 8;
        f32x4 acc[8];
#pragma unroll
        for (int mi = 0; mi < 8; ++mi) acc[mi] = (f32x4){0.f, 0.f, 0.f, 0.f};
#pragma unroll 2
        for (int d4 = 0; d4 < 64; ++d4) {
            const f32x4 xv = xs[r][d4 ^ sw];
#pragma unroll
            for (int mi = 0; mi < 8; ++mi) {
                const f32x4 ev = *reinterpret_cast<const f32x4*>(e + (m0 + mi) * D + d4 * 4);
                acc[mi].x = fmaf(xv.x, ev.x, acc[mi].x);
                acc[mi].y = fmaf(xv.y, ev.y, acc[mi].y);
                acc[mi].z = fmaf(xv.z, ev.z, acc[mi].z);
                acc[mi].w = fmaf(xv.w, ev.w, acc[mi].w);
            }
        }
#pragma unroll
        for (int mi = 0; mi < 8; ++mi) {
            float dot = (acc[mi].x + acc[mi].y) + (acc[mi].z + acc[mi].w);
            float val = enorm[m0 + mi] - 2.0f * dot;
            if (val < bestVal) { bestVal = val; bestIdx = m0 + mi; }
        }
    }
    cval[c][r] = bestVal;
    cidx[c][r] = bestIdx;
    __syncthreads();

    if (c == 0) {
        float bv = bestVal; int bi = bestIdx;
#pragma unroll
        for (int cc = 1; cc < 4; ++cc) {
            float v = cval[cc][r]; int i = cidx[cc][r];
            if (v < bv || (v == bv && i < bi)) { bv = v; bi = i; }
        }
        fidx[r] = bi;
        outIdx[row0 + r] = (float)bi;
        atomicAdd(ws + 1 + bi, 1.0f);
        float dist = bv + xnorm;
#pragma unroll
        for (int o = 32; o > 0; o >>= 1) dist += __shfl_down(dist, o, 64);
        if (r == 0) atomicAdd(ws, dist);
    }
    __syncthreads();

#pragma unroll
    for (int it = 0; it < 16; ++it) {
        int f  = it * 256 + tid;
        int rr = f >> 6, c4 = f & 63;
        int idx = fidx[rr];
        f32x4 v = *reinterpret_cast<const f32x4*>(e + idx * D + c4 * 4);
        *reinterpret_cast<f32x4*>(outQ + (row0 + rr) * D + c4 * 4) = v;
    }
}

// ---------------- finalize: loss + perplexity ----------------
__global__ void vq_final_kernel(const float* __restrict__ ws,
                                float* __restrict__ outLoss, float* __restrict__ outPpl,
                                float invN, float invND) {
    int t = threadIdx.x;  // 1024 threads, one bin each
    float p = ws[1 + t] * invN;
    float term = p * logf(p + 1e-10f);
#pragma unroll
    for (int o = 32; o > 0; o >>= 1) term += __shfl_down(term, o, 64);
    __shared__ float s[16];
    if ((t & 63) == 0) s[t >> 6] = term;
    __syncthreads();
    if (t == 0) {
        float tot = 0.f;
#pragma unroll
        for (int i = 0; i < 16; ++i) tot += s[i];
        *outPpl  = expf(-tot);
        *outLoss = 1.25f * ws[0] * invND;
    }
}

extern "C" void kernel_launch(void* const* d_in, const int* in_sizes, int n_in,
                              void* d_out, int out_size, void* d_ws, size_t ws_size,
                              hipStream_t stream) {
    const float* x = (const float*)d_in[0];
    const float* e = (const float*)d_in[1];
    const int NX = in_sizes[0];     // N*D = 8388608
    const int N  = NX / D;          // 32768

    float* out     = (float*)d_out;
    float* outQ    = out;
    float* outLoss = out + NX;
    float* outIdx  = out + NX + 1;
    float* outPpl  = out + NX + 1 + N;
    float* ws      = (float*)d_ws;

    (void)hipMemsetAsync(d_ws, 0, (1 + M) * sizeof(float), stream);
    if (ws_size >= WS_NEEDED) {
        prep_kernel<<<M, 64, 0, stream>>>(e, ws);
        vq_mfma_kernel<<<N / ROWS, 256, 0, stream>>>(x, e, outQ, outIdx, ws);
    } else {
        enorm_kernel<<<M, 64, 0, stream>>>(e, ws + WS_ENORM_F);
        vq_main_kernel<<<N / 64, 256, 0, stream>>>(x, e, outQ, outIdx, ws);
    }
    vq_final_kernel<<<1, 1024, 0, stream>>>(ws, outLoss, outPpl,
                                            1.0f / (float)N, 1.0f / (float)NX);
}

// Round 6
// 97.210 us; speedup vs baseline: 2.3589x; 1.6112x over previous
//
#include <hip/hip_runtime.h>

// VQEmbedding: x [N=32768, D=256] fp32, embedding [M=1024, D=256] fp32.
// Outputs (flat fp32): quantized [N*D], loss [1], indices [N] (as float), perplexity [1].
// R6: e-slices resident in REGISTERS (split-f16 A-frags, 32 embs/wave), x streamed
// through double-buffered swizzled LDS in 32-row chunks. Cross-slice argmin via
// sortable (val,idx) u64 atomicMin. Separate gather kernel decodes + writes outputs.
// dist = ||e||^2 - 2 x.e (argmin-equivalent); loss = 1.25*(sum bestdist + ||x||_F^2)/(N*D).

constexpr int D = 256;
constexpr int M = 1024;
constexpr int SLICES = 4;     // M / 256
constexpr int CHUNK = 32;     // x rows per stage
constexpr int RPB = 512;      // x rows per block (16 chunks)

typedef _Float16 f16;
typedef __attribute__((ext_vector_type(4))) _Float16 f16x4;
typedef __attribute__((ext_vector_type(8))) _Float16 f16x8;
typedef __attribute__((ext_vector_type(4))) float f32x4;
typedef unsigned long long u64;
typedef unsigned int u32;

// ws layout (bytes):
//   [0..4)        loss accumulator (float)
//   [4..4100)     counts (1024 floats, float-idx 1..1025)
//   [4112..8208)  enorm (fallback path only, float-idx 1028..2052)
//   [16384..16384+N*8)  argmin keys (u64 per row)
constexpr size_t WS_ENORM_F = 1028;
constexpr size_t WS_KEYS_B  = 16384;

__device__ inline u64 makekey(float v, int idx) {
    u32 b = __float_as_uint(v);
    u32 enc = (b & 0x80000000u) ? ~b : (b | 0x80000000u);   // monotone-sortable
    return ((u64)enc << 32) | (u32)idx;                      // low idx wins ties
}

// ---------------- main kernel: e-in-regs, stream x ----------------
__global__ __launch_bounds__(512, 2) void vq_dist_kernel(
    const float* __restrict__ x, const float* __restrict__ e,
    u64* __restrict__ keys, float* __restrict__ ws, int groups)
{
    __shared__ ushort xH[2][CHUNK * D];   // 16 KB each buf, XOR-swizzled
    __shared__ ushort xL[2][CHUNK * D];
    __shared__ u64    wred[8][CHUNK];

    const int tid = threadIdx.x;
    const int w  = __builtin_amdgcn_readfirstlane(tid >> 6);  // wave id
    const int l  = tid & 63;
    const int lr = l & 15;       // frag row/col
    const int q  = l >> 4;       // k-group
    const int bswz = (lr & 7) << 4;

    const int slice = blockIdx.x / groups;     // siblings share bid%8 -> same XCD
    const int group = blockIdx.x % groups;
    const int grow0 = group * RPB;
    const int ebase = slice * 256 + w * 32;    // this wave's 32 embeddings

    // ---- prologue: e rows -> split-f16 registers; enorm via in-lane sq + shfl ----
    f16x8 Ah[2][8], Al[2][8];
    float enR[2];
#pragma unroll
    for (int rf = 0; rf < 2; ++rf) {
        float sq = 0.f;
#pragma unroll
        for (int kk = 0; kk < 8; ++kk) {
            const float* p = e + (size_t)(ebase + rf * 16 + lr) * D + kk * 32 + q * 8;
            f32x4 a = *reinterpret_cast<const f32x4*>(p);
            f32x4 b = *reinterpret_cast<const f32x4*>(p + 4);
            f16 h0=(f16)a.x,h1=(f16)a.y,h2=(f16)a.z,h3=(f16)a.w;
            f16 h4=(f16)b.x,h5=(f16)b.y,h6=(f16)b.z,h7=(f16)b.w;
            Ah[rf][kk] = (f16x8){h0,h1,h2,h3,h4,h5,h6,h7};
            Al[rf][kk] = (f16x8){(f16)(a.x-(float)h0),(f16)(a.y-(float)h1),
                                 (f16)(a.z-(float)h2),(f16)(a.w-(float)h3),
                                 (f16)(b.x-(float)h4),(f16)(b.y-(float)h5),
                                 (f16)(b.z-(float)h6),(f16)(b.w-(float)h7)};
            sq = fmaf(a.x,a.x,fmaf(a.y,a.y,fmaf(a.z,a.z,fmaf(a.w,a.w,
                 fmaf(b.x,b.x,fmaf(b.y,b.y,fmaf(b.z,b.z,fmaf(b.w,b.w,sq))))))));
        }
        sq += __shfl_xor(sq, 16, 64);   // sum the 4 q-groups -> full ||e_row||^2
        sq += __shfl_xor(sq, 32, 64);
        enR[rf] = sq;
    }
    // enorm for this lane's acc rows (rf*16 + q*4 + i): fetch from lane lr'=q*4+i
    float enA[2][4];
#pragma unroll
    for (int rf = 0; rf < 2; ++rf)
#pragma unroll
        for (int i = 0; i < 4; ++i)
            enA[rf][i] = __shfl(enR[rf], (l & 48) | (q * 4 + i), 64);

    // ---- stage chunk 0 ----
    float sxx = 0.f;
    f32x4 st[4];
#pragma unroll
    for (int i = 0; i < 4; ++i) {
        int f = i * 512 + tid, rr = f >> 6, c4 = f & 63;
        st[i] = *reinterpret_cast<const f32x4*>(x + (size_t)(grow0 + rr) * D + c4 * 4);
    }
    auto stage_write = [&](int nb) {
#pragma unroll
        for (int i = 0; i < 4; ++i) {
            int f = i * 512 + tid, rr = f >> 6, c4 = f & 63;
            f32x4 v = st[i];
            sxx = fmaf(v.x,v.x,fmaf(v.y,v.y,fmaf(v.z,v.z,fmaf(v.w,v.w,sxx))));
            f16 h0=(f16)v.x,h1=(f16)v.y,h2=(f16)v.z,h3=(f16)v.w;
            int byte = (rr * 512 + c4 * 8) ^ ((rr & 7) << 4);
            *reinterpret_cast<f16x4*>((char*)&xH[nb][0] + byte) = (f16x4){h0,h1,h2,h3};
            *reinterpret_cast<f16x4*>((char*)&xL[nb][0] + byte) =
                (f16x4){(f16)(v.x-(float)h0),(f16)(v.y-(float)h1),
                        (f16)(v.z-(float)h2),(f16)(v.w-(float)h3)};
        }
    };
    stage_write(0);

    const int nch = RPB / CHUNK;   // 16
    for (int c = 0; c < nch; ++c) {
        if (c + 1 < nch) {         // issue next chunk's loads early (hide HBM latency)
#pragma unroll
            for (int i = 0; i < 4; ++i) {
                int f = i * 512 + tid, rr = f >> 6, c4 = f & 63;
                st[i] = *reinterpret_cast<const f32x4*>(
                    x + (size_t)(grow0 + (c + 1) * CHUNK + rr) * D + c4 * 4);
            }
        }
        __syncthreads();           // buf[c&1] staged writes visible
        const int cb = c & 1;

        f32x4 acc[2][2];           // [rf(emb)][cf(xrow)]
#pragma unroll
        for (int rf = 0; rf < 2; ++rf)
#pragma unroll
            for (int cf = 0; cf < 2; ++cf) acc[rf][cf] = (f32x4){0.f,0.f,0.f,0.f};

#pragma unroll
        for (int kk = 0; kk < 8; ++kk) {
            f16x8 Bh[2], Bl[2];
#pragma unroll
            for (int cf = 0; cf < 2; ++cf) {
                int byte = ((cf * 16 + lr) * 512 + kk * 64 + q * 16) ^ bswz;
                Bh[cf] = *reinterpret_cast<const f16x8*>((const char*)&xH[cb][0] + byte);
                Bl[cf] = *reinterpret_cast<const f16x8*>((const char*)&xL[cb][0] + byte);
            }
#pragma unroll
            for (int rf = 0; rf < 2; ++rf)
#pragma unroll
                for (int cf = 0; cf < 2; ++cf) {
                    acc[rf][cf] = __builtin_amdgcn_mfma_f32_16x16x32_f16(Ah[rf][kk], Bh[cf], acc[rf][cf], 0, 0, 0);
                    acc[rf][cf] = __builtin_amdgcn_mfma_f32_16x16x32_f16(Ah[rf][kk], Bl[cf], acc[rf][cf], 0, 0, 0);
                    acc[rf][cf] = __builtin_amdgcn_mfma_f32_16x16x32_f16(Al[rf][kk], Bh[cf], acc[rf][cf], 0, 0, 0);
                }
        }

        // fold per-lane (embs ascend with rf,i -> strict < = first min)
        float bV[2] = {3.4e38f, 3.4e38f};
        int   bI[2] = {0, 0};
#pragma unroll
        for (int rf = 0; rf < 2; ++rf)
#pragma unroll
            for (int i = 0; i < 4; ++i) {
                int   mi = ebase + rf * 16 + q * 4 + i;
                float en = enA[rf][i];
#pragma unroll
                for (int cf = 0; cf < 2; ++cf) {
                    float dv = fmaf(-2.f, acc[rf][cf][i], en);
                    if (dv < bV[cf]) { bV[cf] = dv; bI[cf] = mi; }
                }
            }
        // reduce across q-groups (same x-row), tie -> lower idx
#pragma unroll
        for (int cf = 0; cf < 2; ++cf) {
#pragma unroll
            for (int mk = 16; mk <= 32; mk <<= 1) {
                float ov = __shfl_xor(bV[cf], mk, 64);
                int   oi = __shfl_xor(bI[cf], mk, 64);
                if (ov < bV[cf] || (ov == bV[cf] && oi < bI[cf])) { bV[cf] = ov; bI[cf] = oi; }
            }
        }
        if (q == 0) {
            wred[w][lr]      = makekey(bV[0], bI[0]);
            wred[w][16 + lr] = makekey(bV[1], bI[1]);
        }
        __syncthreads();           // wred visible; all reads of buf[(c+1)&1] done

        if (tid < 32) {            // merge 8 waves, one atomic per row
            u64 k = wred[0][tid];
#pragma unroll
            for (int ww = 1; ww < 8; ++ww) { u64 k2 = wred[ww][tid]; k = (k2 < k) ? k2 : k; }
            atomicMin(&keys[grow0 + c * CHUNK + tid], k);
        }
        if (c + 1 < nch) stage_write((c + 1) & 1);
    }

    if (slice == 0) {              // ||x||_F^2 counted exactly once
#pragma unroll
        for (int o = 32; o > 0; o >>= 1) sxx += __shfl_down(sxx, o, 64);
        if (l == 0) atomicAdd(ws, sxx);
    }
}

// ---------------- gather: decode keys -> idx/counts/loss + outQ ----------------
__global__ __launch_bounds__(256) void vq_gather_kernel(
    const float* __restrict__ e, const u64* __restrict__ keys,
    float* __restrict__ outQ, float* __restrict__ outIdx, float* __restrict__ ws)
{
    __shared__ int fidx[64];
    const int tid = threadIdx.x, row0 = blockIdx.x * 64;
    if (tid < 64) {
        u64 k = keys[row0 + tid];
        u32 enc = (u32)(k >> 32);
        u32 bits = (enc & 0x80000000u) ? (enc & 0x7fffffffu) : ~enc;
        float bv = __uint_as_float(bits);
        int idx = (int)(u32)(k & 0xffffffffu);
        fidx[tid] = idx;
        outIdx[row0 + tid] = (float)idx;
        atomicAdd(ws + 1 + idx, 1.0f);
        float s = bv;
#pragma unroll
        for (int o = 32; o > 0; o >>= 1) s += __shfl_down(s, o, 64);
        if (tid == 0) atomicAdd(ws, s);
    }
    __syncthreads();
#pragma unroll
    for (int it = 0; it < 16; ++it) {
        int f = it * 256 + tid, rr = f >> 6, c4 = f & 63;
        f32x4 v = *reinterpret_cast<const f32x4*>(e + (size_t)fidx[rr] * D + c4 * 4);
        __builtin_nontemporal_store(v, reinterpret_cast<f32x4*>(outQ + (size_t)(row0 + rr) * D + c4 * 4));
    }
}

// ---------------- fallback fp32 path (only if ws too small) ----------------
__global__ void enorm_kernel(const float* __restrict__ e, float* __restrict__ enorm) {
    int m = blockIdx.x, l = threadIdx.x;
    const f32x4 v = *reinterpret_cast<const f32x4*>(e + m * D + l * 4);
    float s = fmaf(v.x, v.x, fmaf(v.y, v.y, fmaf(v.z, v.z, v.w * v.w)));
#pragma unroll
    for (int o = 32; o > 0; o >>= 1) s += __shfl_down(s, o, 64);
    if (l == 0) enorm[m] = s;
}

__global__ __launch_bounds__(256, 2) void vq_main_kernel(
    const float* __restrict__ x, const float* __restrict__ e,
    float* __restrict__ outQ, float* __restrict__ outIdx, float* __restrict__ ws) {
    __shared__ f32x4 xs[64][64];
    __shared__ float cval[4][64];
    __shared__ int   cidx[4][64];
    __shared__ int   fidx[64];
    const int tid = threadIdx.x, row0 = blockIdx.x * 64;
#pragma unroll
    for (int it = 0; it < 16; ++it) {
        int f = it * 256 + tid, rr = f >> 6, c4 = f & 63;
        xs[rr][c4 ^ (rr & 7)] = *reinterpret_cast<const f32x4*>(x + (row0 + rr) * D + c4 * 4);
    }
    __syncthreads();
    const int r = tid & 63, c = __builtin_amdgcn_readfirstlane(tid >> 6), sw = r & 7;
    float xnorm = 0.f;
    if (c == 0) {
        f32x4 a = (f32x4){0.f,0.f,0.f,0.f};
        for (int d4 = 0; d4 < 64; ++d4) {
            f32x4 xv = xs[r][d4 ^ sw];
            a.x = fmaf(xv.x, xv.x, a.x); a.y = fmaf(xv.y, xv.y, a.y);
            a.z = fmaf(xv.z, xv.z, a.z); a.w = fmaf(xv.w, xv.w, a.w);
        }
        xnorm = (a.x + a.y) + (a.z + a.w);
    }
    const float* __restrict__ enorm = ws + WS_ENORM_F;
    float bestVal = 3.4e38f; int bestIdx = 0;
    for (int chunk = 0; chunk < M / 32; ++chunk) {
        const int m0 = chunk * 32 + c * 8;
        f32x4 acc[8];
#pragma unroll
        for (int mi = 0; mi < 8; ++mi) acc[mi] = (f32x4){0.f,0.f,0.f,0.f};
#pragma unroll 2
        for (int d4 = 0; d4 < 64; ++d4) {
            const f32x4 xv = xs[r][d4 ^ sw];
#pragma unroll
            for (int mi = 0; mi < 8; ++mi) {
                const f32x4 ev = *reinterpret_cast<const f32x4*>(e + (m0 + mi) * D + d4 * 4);
                acc[mi].x = fmaf(xv.x, ev.x, acc[mi].x); acc[mi].y = fmaf(xv.y, ev.y, acc[mi].y);
                acc[mi].z = fmaf(xv.z, ev.z, acc[mi].z); acc[mi].w = fmaf(xv.w, ev.w, acc[mi].w);
            }
        }
#pragma unroll
        for (int mi = 0; mi < 8; ++mi) {
            float dot = (acc[mi].x + acc[mi].y) + (acc[mi].z + acc[mi].w);
            float val = enorm[m0 + mi] - 2.0f * dot;
            if (val < bestVal) { bestVal = val; bestIdx = m0 + mi; }
        }
    }
    cval[c][r] = bestVal; cidx[c][r] = bestIdx;
    __syncthreads();
    if (c == 0) {
        float bv = bestVal; int bi = bestIdx;
#pragma unroll
        for (int cc = 1; cc < 4; ++cc) {
            float v = cval[cc][r]; int i = cidx[cc][r];
            if (v < bv || (v == bv && i < bi)) { bv = v; bi = i; }
        }
        fidx[r] = bi; outIdx[row0 + r] = (float)bi;
        atomicAdd(ws + 1 + bi, 1.0f);
        float dist = bv + xnorm;
#pragma unroll
        for (int o = 32; o > 0; o >>= 1) dist += __shfl_down(dist, o, 64);
        if (r == 0) atomicAdd(ws, dist);
    }
    __syncthreads();
#pragma unroll
    for (int it = 0; it < 16; ++it) {
        int f = it * 256 + tid, rr = f >> 6, c4 = f & 63;
        *reinterpret_cast<f32x4*>(outQ + (row0 + rr) * D + c4 * 4) =
            *reinterpret_cast<const f32x4*>(e + fidx[rr] * D + c4 * 4);
    }
}

// ---------------- finalize: loss + perplexity ----------------
__global__ void vq_final_kernel(const float* __restrict__ ws,
                                float* __restrict__ outLoss, float* __restrict__ outPpl,
                                float invN, float invND) {
    int t = threadIdx.x;
    float p = ws[1 + t] * invN;
    float term = p * logf(p + 1e-10f);
#pragma unroll
    for (int o = 32; o > 0; o >>= 1) term += __shfl_down(term, o, 64);
    __shared__ float s[16];
    if ((t & 63) == 0) s[t >> 6] = term;
    __syncthreads();
    if (t == 0) {
        float tot = 0.f;
#pragma unroll
        for (int i = 0; i < 16; ++i) tot += s[i];
        *outPpl  = expf(-tot);
        *outLoss = 1.25f * ws[0] * invND;
    }
}

extern "C" void kernel_launch(void* const* d_in, const int* in_sizes, int n_in,
                              void* d_out, int out_size, void* d_ws, size_t ws_size,
                              hipStream_t stream) {
    const float* x = (const float*)d_in[0];
    const float* e = (const float*)d_in[1];
    const int NX = in_sizes[0];     // N*D = 8388608
    const int N  = NX / D;          // 32768

    float* out     = (float*)d_out;
    float* outQ    = out;
    float* outLoss = out + NX;
    float* outIdx  = out + NX + 1;
    float* outPpl  = out + NX + 1 + N;
    float* ws      = (float*)d_ws;
    u64*   keys    = (u64*)((char*)d_ws + WS_KEYS_B);

    const size_t need = WS_KEYS_B + (size_t)N * 8;
    (void)hipMemsetAsync(d_ws, 0, 4100, stream);    // loss + counts
    if (ws_size >= need && (N % RPB) == 0) {
        (void)hipMemsetAsync(keys, 0xFF, (size_t)N * 8, stream);  // keys = +inf
        const int groups = N / RPB;
        vq_dist_kernel<<<SLICES * groups, 512, 0, stream>>>(x, e, keys, ws, groups);
        vq_gather_kernel<<<N / 64, 256, 0, stream>>>(e, keys, outQ, outIdx, ws);
    } else {
        enorm_kernel<<<M, 64, 0, stream>>>(e, ws + WS_ENORM_F);
        vq_main_kernel<<<N / 64, 256, 0, stream>>>(x, e, outQ, outIdx, ws);
    }
    vq_final_kernel<<<1, 1024, 0, stream>>>(ws, outLoss, outPpl,
                                            1.0f / (float)N, 1.0f / (float)NX);
}

// Round 7
// 93.713 us; speedup vs baseline: 2.4470x; 1.0373x over previous
//
#include <hip/hip_runtime.h>

// VQEmbedding: x [N=32768, D=256] fp32, embedding [M=1024, D=256] fp32.
// Outputs (flat fp32): quantized [N*D], loss [1], indices [N] (as float), perplexity [1].
// R7: FUSED single main kernel. x rows live in registers (split f16 hi/lo, 32 rows/wave,
// 128 rows/block) -> each row owned by ONE block: argmin finishes locally, gather+outIdx+
// counts+loss fused, no keys/atomicMin. e pre-split into a fragment-ordered hi/lo f16
// table staged via global_load_lds (no staging VALU, conflict-free lane-linear LDS).
// dist = ||e||^2 - 2 x.e ; loss = 1.25*(sum bestdist + ||x||_F^2)/(N*D).

constexpr int D = 256;
constexpr int M = 1024;

typedef _Float16 f16;
typedef __attribute__((ext_vector_type(8))) _Float16 f16x8;
typedef __attribute__((ext_vector_type(4))) float f32x4;

// ws layout (bytes):
//   [0..4)        loss accumulator (float)
//   [4..4100)     counts (1024 floats, float-idx 1..1025)
//   [4112..8208)  enorm (1024 floats, float-idx 1028..2052)
//   [8320..1056896)  e split-f16 table, fragment-ordered:
//     16B element v (65536 total): lane=v&63, unit=v>>6; rf=unit&1, spl=(unit>>1)&1,
//     kk=(unit>>2)&7, tile=unit>>5; content = split(e[tile*32+rf*16+(lane&15)]
//     [kk*32+(lane>>4)*8 .. +8]), spl0=hi, spl1=lo.
constexpr size_t WS_ENORM_F = 1028;
constexpr size_t WS_TAB_B   = 8320;
constexpr size_t WS_NEEDED  = 1056896;

__device__ inline void gload_lds16(const void* g, void* l) {
    __builtin_amdgcn_global_load_lds(
        (const __attribute__((address_space(1))) unsigned int*)(g),
        (__attribute__((address_space(3))) unsigned int*)(l), 16, 0, 0);
}

// ---------------- prep: fragment-ordered split-f16 e table + exact ||e||^2 ----------------
__global__ __launch_bounds__(256) void prep_kernel(const float* __restrict__ e,
                                                   float* __restrict__ ws) {
    const int b = blockIdx.x, t = threadIdx.x;
    if (b < 256) {
        int v    = b * 256 + t;               // 16B element index
        int lane = v & 63, unit = v >> 6;
        int rf = unit & 1, spl = (unit >> 1) & 1, kk = (unit >> 2) & 7, tile = unit >> 5;
        int lr = lane & 15, q = lane >> 4;
        const float* p = e + (size_t)(tile * 32 + rf * 16 + lr) * D + kk * 32 + q * 8;
        f32x4 a = *reinterpret_cast<const f32x4*>(p);
        f32x4 c = *reinterpret_cast<const f32x4*>(p + 4);
        f16 h0=(f16)a.x,h1=(f16)a.y,h2=(f16)a.z,h3=(f16)a.w;
        f16 h4=(f16)c.x,h5=(f16)c.y,h6=(f16)c.z,h7=(f16)c.w;
        f16x8 out;
        if (spl == 0) out = (f16x8){h0,h1,h2,h3,h4,h5,h6,h7};
        else          out = (f16x8){(f16)(a.x-(float)h0),(f16)(a.y-(float)h1),
                                    (f16)(a.z-(float)h2),(f16)(a.w-(float)h3),
                                    (f16)(c.x-(float)h4),(f16)(c.y-(float)h5),
                                    (f16)(c.z-(float)h6),(f16)(c.w-(float)h7)};
        *reinterpret_cast<f16x8*>((char*)ws + WS_TAB_B + (size_t)v * 16) = out;
    } else {
        int row  = (b - 256) * 4 + (t >> 6);  // 1024 rows over blocks 256..511
        int lane = t & 63;
        f32x4 a = *reinterpret_cast<const f32x4*>(e + (size_t)row * D + lane * 4);
        float s = fmaf(a.x, a.x, fmaf(a.y, a.y, fmaf(a.z, a.z, a.w * a.w)));
#pragma unroll
        for (int o = 32; o > 0; o >>= 1) s += __shfl_down(s, o, 64);
        if (lane == 0) ws[WS_ENORM_F + row] = s;
    }
}

// ---------------- fused main kernel: x-in-regs, stream e table via global_load_lds --------
__global__ __launch_bounds__(256, 2) void vq_fused_kernel(
    const float* __restrict__ x, const float* __restrict__ e,
    float* __restrict__ outQ, float* __restrict__ outIdx, float* __restrict__ ws)
{
    __shared__ ushort ebuf[2][16384];   // 2 x 32 KB e-tile (32 embs, hi+lo), lane-linear
    __shared__ float  en_s[M];          // 4 KB
    __shared__ int    fidx[128];
    __shared__ float  lsum[4];

    const int tid = threadIdx.x;
    const int w   = __builtin_amdgcn_readfirstlane(tid >> 6);
    const int l   = tid & 63;
    const int lr  = l & 15, q = l >> 4;
    const int R   = blockIdx.x * 128;   // block-owned x rows [R, R+128)
    const char* tab = (const char*)ws + WS_TAB_B;

    // enorm -> LDS
    {
        f32x4 v = *reinterpret_cast<const f32x4*>(ws + WS_ENORM_F + tid * 4);
        *reinterpret_cast<f32x4*>(&en_s[tid * 4]) = v;
    }

    // x rows -> split-f16 registers (wave w owns rows R+w*32..+32), exact row norms
    f16x8 Xh[2][8], Xl[2][8];
    float xn[2];
#pragma unroll
    for (int cf = 0; cf < 2; ++cf) {
        float s = 0.f;
#pragma unroll
        for (int kk = 0; kk < 8; ++kk) {
            const float* p = x + (size_t)(R + w * 32 + cf * 16 + lr) * D + kk * 32 + q * 8;
            f32x4 a = *reinterpret_cast<const f32x4*>(p);
            f32x4 c = *reinterpret_cast<const f32x4*>(p + 4);
            f16 h0=(f16)a.x,h1=(f16)a.y,h2=(f16)a.z,h3=(f16)a.w;
            f16 h4=(f16)c.x,h5=(f16)c.y,h6=(f16)c.z,h7=(f16)c.w;
            Xh[cf][kk] = (f16x8){h0,h1,h2,h3,h4,h5,h6,h7};
            Xl[cf][kk] = (f16x8){(f16)(a.x-(float)h0),(f16)(a.y-(float)h1),
                                 (f16)(a.z-(float)h2),(f16)(a.w-(float)h3),
                                 (f16)(c.x-(float)h4),(f16)(c.y-(float)h5),
                                 (f16)(c.z-(float)h6),(f16)(c.w-(float)h7)};
            s = fmaf(a.x,a.x,fmaf(a.y,a.y,fmaf(a.z,a.z,fmaf(a.w,a.w,
                fmaf(c.x,c.x,fmaf(c.y,c.y,fmaf(c.z,c.z,fmaf(c.w,c.w,s))))))));
        }
        s += __shfl_xor(s, 16, 64);     // sum 4 q-groups -> full ||x_row||^2
        s += __shfl_xor(s, 32, 64);
        xn[cf] = s;
    }

    // stage tile 0 (8 x 1KB wave-instructions per wave; LDS dest wave-uniform base)
#pragma unroll
    for (int i = 0; i < 8; ++i)
        gload_lds16(tab + (w * 8 + i) * 1024 + l * 16, &ebuf[0][(w * 8 + i) * 512]);
    __syncthreads();

    float bV[2] = {3.4e38f, 3.4e38f};
    int   bI[2] = {0, 0};

    for (int t = 0; t < 32; ++t) {      // 32 e-tiles of 32 embeddings
        const ushort* eb = &ebuf[t & 1][0];
        if (t < 31) {                   // prefetch next tile into other buffer
            const char* gt = tab + (size_t)(t + 1) * 32768;
            ushort* lb = &ebuf[(t + 1) & 1][0];
#pragma unroll
            for (int i = 0; i < 8; ++i)
                gload_lds16(gt + (w * 8 + i) * 1024 + l * 16, lb + (w * 8 + i) * 512);
        }

        f32x4 acc[2][2];                // [rf(emb)][cf(xrow)]
#pragma unroll
        for (int rf = 0; rf < 2; ++rf)
#pragma unroll
            for (int cf = 0; cf < 2; ++cf) acc[rf][cf] = (f32x4){0.f,0.f,0.f,0.f};

#pragma unroll
        for (int kk = 0; kk < 8; ++kk) {
            // lane-linear conflict-free ds_read_b128: unit u = kk*4 + spl*2 + rf
            f16x8 Ah0 = *reinterpret_cast<const f16x8*>(eb + (kk*4+0)*512 + l*8);
            f16x8 Ah1 = *reinterpret_cast<const f16x8*>(eb + (kk*4+1)*512 + l*8);
            f16x8 Al0 = *reinterpret_cast<const f16x8*>(eb + (kk*4+2)*512 + l*8);
            f16x8 Al1 = *reinterpret_cast<const f16x8*>(eb + (kk*4+3)*512 + l*8);
#pragma unroll
            for (int cf = 0; cf < 2; ++cf) {
                acc[0][cf] = __builtin_amdgcn_mfma_f32_16x16x32_f16(Ah0, Xh[cf][kk], acc[0][cf], 0, 0, 0);
                acc[0][cf] = __builtin_amdgcn_mfma_f32_16x16x32_f16(Ah0, Xl[cf][kk], acc[0][cf], 0, 0, 0);
                acc[0][cf] = __builtin_amdgcn_mfma_f32_16x16x32_f16(Al0, Xh[cf][kk], acc[0][cf], 0, 0, 0);
                acc[1][cf] = __builtin_amdgcn_mfma_f32_16x16x32_f16(Ah1, Xh[cf][kk], acc[1][cf], 0, 0, 0);
                acc[1][cf] = __builtin_amdgcn_mfma_f32_16x16x32_f16(Ah1, Xl[cf][kk], acc[1][cf], 0, 0, 0);
                acc[1][cf] = __builtin_amdgcn_mfma_f32_16x16x32_f16(Al1, Xh[cf][kk], acc[1][cf], 0, 0, 0);
            }
        }

        // fold distances (emb index ascends with t,rf,i -> strict < = first min)
#pragma unroll
        for (int rf = 0; rf < 2; ++rf)
#pragma unroll
            for (int i = 0; i < 4; ++i) {
                int   mi = t * 32 + rf * 16 + q * 4 + i;
                float en = en_s[mi];
#pragma unroll
                for (int cf = 0; cf < 2; ++cf) {
                    float dv = fmaf(-2.f, acc[rf][cf][i], en);
                    if (dv < bV[cf]) { bV[cf] = dv; bI[cf] = mi; }
                }
            }
        __syncthreads();                // staged tile t+1 complete; reads of eb done
    }

    // reduce across q-groups (lanes sharing an x-row), tie -> lower idx
#pragma unroll
    for (int cf = 0; cf < 2; ++cf) {
#pragma unroll
        for (int mk = 16; mk <= 32; mk <<= 1) {
            float ov = __shfl_xor(bV[cf], mk, 64);
            int   oi = __shfl_xor(bI[cf], mk, 64);
            if (ov < bV[cf] || (ov == bV[cf] && oi < bI[cf])) { bV[cf] = ov; bI[cf] = oi; }
        }
    }
    if (q == 0) {
        fidx[w * 32 + lr]      = bI[0];
        fidx[w * 32 + 16 + lr] = bI[1];
        outIdx[R + w * 32 + lr]      = (float)bI[0];
        outIdx[R + w * 32 + 16 + lr] = (float)bI[1];
        atomicAdd(ws + 1 + bI[0], 1.0f);
        atomicAdd(ws + 1 + bI[1], 1.0f);
        float ls = bV[0] + bV[1] + xn[0] + xn[1];
#pragma unroll
        for (int o = 8; o > 0; o >>= 1) ls += __shfl_down(ls, o, 64);
        if (lr == 0) lsum[w] = ls;
    }
    __syncthreads();
    if (tid == 0) atomicAdd(ws, lsum[0] + lsum[1] + lsum[2] + lsum[3]);

    // fused gather: quantized = embedding[idx] (exact fp32), nontemporal store
#pragma unroll
    for (int it = 0; it < 32; ++it) {
        int u = it * 256 + tid;
        int row = u >> 6, c4 = u & 63;  // 128 rows x 64 f32x4 units
        f32x4 v = *reinterpret_cast<const f32x4*>(e + (size_t)fidx[row] * D + c4 * 4);
        __builtin_nontemporal_store(v, reinterpret_cast<f32x4*>(outQ + (size_t)(R + row) * D + c4 * 4));
    }
}

// ---------------- fallback fp32 path (only if ws too small) ----------------
__global__ void enorm_kernel(const float* __restrict__ e, float* __restrict__ enorm) {
    int m = blockIdx.x, l = threadIdx.x;
    const f32x4 v = *reinterpret_cast<const f32x4*>(e + m * D + l * 4);
    float s = fmaf(v.x, v.x, fmaf(v.y, v.y, fmaf(v.z, v.z, v.w * v.w)));
#pragma unroll
    for (int o = 32; o > 0; o >>= 1) s += __shfl_down(s, o, 64);
    if (l == 0) enorm[m] = s;
}

__global__ __launch_bounds__(256, 2) void vq_main_kernel(
    const float* __restrict__ x, const float* __restrict__ e,
    float* __restrict__ outQ, float* __restrict__ outIdx, float* __restrict__ ws) {
    __shared__ f32x4 xs[64][64];
    __shared__ float cval[4][64];
    __shared__ int   cidx[4][64];
    __shared__ int   fidx[64];
    const int tid = threadIdx.x, row0 = blockIdx.x * 64;
#pragma unroll
    for (int it = 0; it < 16; ++it) {
        int f = it * 256 + tid, rr = f >> 6, c4 = f & 63;
        xs[rr][c4 ^ (rr & 7)] = *reinterpret_cast<const f32x4*>(x + (row0 + rr) * D + c4 * 4);
    }
    __syncthreads();
    const int r = tid & 63, c = __builtin_amdgcn_readfirstlane(tid >> 6), sw = r & 7;
    float xnorm = 0.f;
    if (c == 0) {
        f32x4 a = (f32x4){0.f,0.f,0.f,0.f};
        for (int d4 = 0; d4 < 64; ++d4) {
            f32x4 xv = xs[r][d4 ^ sw];
            a.x = fmaf(xv.x, xv.x, a.x); a.y = fmaf(xv.y, xv.y, a.y);
            a.z = fmaf(xv.z, xv.z, a.z); a.w = fmaf(xv.w, xv.w, a.w);
        }
        xnorm = (a.x + a.y) + (a.z + a.w);
    }
    const float* __restrict__ enorm = ws + WS_ENORM_F;
    float bestVal = 3.4e38f; int bestIdx = 0;
    for (int chunk = 0; chunk < M / 32; ++chunk) {
        const int m0 = chunk * 32 + c * 8;
        f32x4 acc[8];
#pragma unroll
        for (int mi = 0; mi < 8; ++mi) acc[mi] = (f32x4){0.f,0.f,0.f,0.f};
#pragma unroll 2
        for (int d4 = 0; d4 < 64; ++d4) {
            const f32x4 xv = xs[r][d4 ^ sw];
#pragma unroll
            for (int mi = 0; mi < 8; ++mi) {
                const f32x4 ev = *reinterpret_cast<const f32x4*>(e + (m0 + mi) * D + d4 * 4);
                acc[mi].x = fmaf(xv.x, ev.x, acc[mi].x); acc[mi].y = fmaf(xv.y, ev.y, acc[mi].y);
                acc[mi].z = fmaf(xv.z, ev.z, acc[mi].z); acc[mi].w = fmaf(xv.w, ev.w, acc[mi].w);
            }
        }
#pragma unroll
        for (int mi = 0; mi < 8; ++mi) {
            float dot = (acc[mi].x + acc[mi].y) + (acc[mi].z + acc[mi].w);
            float val = enorm[m0 + mi] - 2.0f * dot;
            if (val < bestVal) { bestVal = val; bestIdx = m0 + mi; }
        }
    }
    cval[c][r] = bestVal; cidx[c][r] = bestIdx;
    __syncthreads();
    if (c == 0) {
        float bv = bestVal; int bi = bestIdx;
#pragma unroll
        for (int cc = 1; cc < 4; ++cc) {
            float v = cval[cc][r]; int i = cidx[cc][r];
            if (v < bv || (v == bv && i < bi)) { bv = v; bi = i; }
        }
        fidx[r] = bi; outIdx[row0 + r] = (float)bi;
        atomicAdd(ws + 1 + bi, 1.0f);
        float dist = bv + xnorm;
#pragma unroll
        for (int o = 32; o > 0; o >>= 1) dist += __shfl_down(dist, o, 64);
        if (r == 0) atomicAdd(ws, dist);
    }
    __syncthreads();
#pragma unroll
    for (int it = 0; it < 16; ++it) {
        int f = it * 256 + tid, rr = f >> 6, c4 = f & 63;
        *reinterpret_cast<f32x4*>(outQ + (row0 + rr) * D + c4 * 4) =
            *reinterpret_cast<const f32x4*>(e + fidx[rr] * D + c4 * 4);
    }
}

// ---------------- finalize: loss + perplexity ----------------
__global__ void vq_final_kernel(const float* __restrict__ ws,
                                float* __restrict__ outLoss, float* __restrict__ outPpl,
                                float invN, float invND) {
    int t = threadIdx.x;
    float p = ws[1 + t] * invN;
    float term = p * logf(p + 1e-10f);
#pragma unroll
    for (int o = 32; o > 0; o >>= 1) term += __shfl_down(term, o, 64);
    __shared__ float s[16];
    if ((t & 63) == 0) s[t >> 6] = term;
    __syncthreads();
    if (t == 0) {
        float tot = 0.f;
#pragma unroll
        for (int i = 0; i < 16; ++i) tot += s[i];
        *outPpl  = expf(-tot);
        *outLoss = 1.25f * ws[0] * invND;
    }
}

extern "C" void kernel_launch(void* const* d_in, const int* in_sizes, int n_in,
                              void* d_out, int out_size, void* d_ws, size_t ws_size,
                              hipStream_t stream) {
    const float* x = (const float*)d_in[0];
    const float* e = (const float*)d_in[1];
    const int NX = in_sizes[0];     // N*D = 8388608
    const int N  = NX / D;          // 32768

    float* out     = (float*)d_out;
    float* outQ    = out;
    float* outLoss = out + NX;
    float* outIdx  = out + NX + 1;
    float* outPpl  = out + NX + 1 + N;
    float* ws      = (float*)d_ws;

    (void)hipMemsetAsync(d_ws, 0, 4100, stream);    // loss + counts
    if (ws_size >= WS_NEEDED && (N % 128) == 0) {
        prep_kernel<<<512, 256, 0, stream>>>(e, ws);
        vq_fused_kernel<<<N / 128, 256, 0, stream>>>(x, e, outQ, outIdx, ws);
    } else {
        enorm_kernel<<<M, 64, 0, stream>>>(e, ws + WS_ENORM_F);
        vq_main_kernel<<<N / 64, 256, 0, stream>>>(x, e, outQ, outIdx, ws);
    }
    vq_final_kernel<<<1, 1024, 0, stream>>>(ws, outLoss, outPpl,
                                            1.0f / (float)N, 1.0f / (float)NX);
}

// Round 8
// 89.375 us; speedup vs baseline: 2.5657x; 1.0485x over previous
//
#include <hip/hip_runtime.h>

// VQEmbedding: x [N=32768, D=256] fp32, embedding [M=1024, D=256] fp32.
// Outputs (flat fp32): quantized [N*D], loss [1], indices [N] (as float), perplexity [1].
// R8: fused kernel, 64 rows/block -> grid=512 (2 independent blocks/CU, barrier
// decoupling), split accumulator chains (accA/accB), enorm via ds_read_b128,
// fold moved after the barrier. e pre-split into fragment-ordered hi/lo f16 table
// staged via global_load_lds (lane-linear, conflict-free).
// dist = ||e||^2 - 2 x.e ; loss = 1.25*(sum bestdist + ||x||_F^2)/(N*D).

constexpr int D = 256;
constexpr int M = 1024;
constexpr int ROWS = 64;   // x rows per block (16 per wave)

typedef _Float16 f16;
typedef __attribute__((ext_vector_type(8))) _Float16 f16x8;
typedef __attribute__((ext_vector_type(4))) float f32x4;

// ws layout (bytes):
//   [0..4)        loss accumulator (float)
//   [4..4100)     counts (1024 floats, float-idx 1..1025)
//   [4112..8208)  enorm (1024 floats, float-idx 1028..2052)
//   [8320..1056896)  e split-f16 table, fragment-ordered:
//     16B element v (65536 total): lane=v&63, unit=v>>6; rf=unit&1, spl=(unit>>1)&1,
//     kk=(unit>>2)&7, tile=unit>>5; content = split(e[tile*32+rf*16+(lane&15)]
//     [kk*32+(lane>>4)*8 .. +8]), spl0=hi, spl1=lo.
constexpr size_t WS_ENORM_F = 1028;
constexpr size_t WS_TAB_B   = 8320;
constexpr size_t WS_NEEDED  = 1056896;

__device__ inline void gload_lds16(const void* g, void* l) {
    __builtin_amdgcn_global_load_lds(
        (const __attribute__((address_space(1))) unsigned int*)(g),
        (__attribute__((address_space(3))) unsigned int*)(l), 16, 0, 0);
}

// ---------------- prep: fragment-ordered split-f16 e table + exact ||e||^2 ----------------
__global__ __launch_bounds__(256) void prep_kernel(const float* __restrict__ e,
                                                   float* __restrict__ ws) {
    const int b = blockIdx.x, t = threadIdx.x;
    if (b < 256) {
        int v    = b * 256 + t;               // 16B element index
        int lane = v & 63, unit = v >> 6;
        int rf = unit & 1, spl = (unit >> 1) & 1, kk = (unit >> 2) & 7, tile = unit >> 5;
        int lr = lane & 15, q = lane >> 4;
        const float* p = e + (size_t)(tile * 32 + rf * 16 + lr) * D + kk * 32 + q * 8;
        f32x4 a = *reinterpret_cast<const f32x4*>(p);
        f32x4 c = *reinterpret_cast<const f32x4*>(p + 4);
        f16 h0=(f16)a.x,h1=(f16)a.y,h2=(f16)a.z,h3=(f16)a.w;
        f16 h4=(f16)c.x,h5=(f16)c.y,h6=(f16)c.z,h7=(f16)c.w;
        f16x8 out;
        if (spl == 0) out = (f16x8){h0,h1,h2,h3,h4,h5,h6,h7};
        else          out = (f16x8){(f16)(a.x-(float)h0),(f16)(a.y-(float)h1),
                                    (f16)(a.z-(float)h2),(f16)(a.w-(float)h3),
                                    (f16)(c.x-(float)h4),(f16)(c.y-(float)h5),
                                    (f16)(c.z-(float)h6),(f16)(c.w-(float)h7)};
        *reinterpret_cast<f16x8*>((char*)ws + WS_TAB_B + (size_t)v * 16) = out;
    } else {
        int row  = (b - 256) * 4 + (t >> 6);  // 1024 rows over blocks 256..511
        int lane = t & 63;
        f32x4 a = *reinterpret_cast<const f32x4*>(e + (size_t)row * D + lane * 4);
        float s = fmaf(a.x, a.x, fmaf(a.y, a.y, fmaf(a.z, a.z, a.w * a.w)));
#pragma unroll
        for (int o = 32; o > 0; o >>= 1) s += __shfl_down(s, o, 64);
        if (lane == 0) ws[WS_ENORM_F + row] = s;
    }
}

// ---------------- fused main kernel: x-in-regs, stream e table via global_load_lds --------
__global__ __launch_bounds__(256, 2) void vq_fused_kernel(
    const float* __restrict__ x, const float* __restrict__ e,
    float* __restrict__ outQ, float* __restrict__ outIdx, float* __restrict__ ws)
{
    __shared__ ushort ebuf[2][16384];   // 2 x 32 KB e-tile (32 embs, hi+lo), lane-linear
    __shared__ float  en_s[M];          // 4 KB
    __shared__ int    fidx[ROWS];
    __shared__ float  lsum[4];

    const int tid = threadIdx.x;
    const int w   = __builtin_amdgcn_readfirstlane(tid >> 6);
    const int l   = tid & 63;
    const int lr  = l & 15, q = l >> 4;
    const int R   = blockIdx.x * ROWS;  // block-owned x rows [R, R+64)
    const char* tab = (const char*)ws + WS_TAB_B;

    // enorm -> LDS
    {
        f32x4 v = *reinterpret_cast<const f32x4*>(ws + WS_ENORM_F + tid * 4);
        *reinterpret_cast<f32x4*>(&en_s[tid * 4]) = v;
    }

    // x rows -> split-f16 registers (wave w owns rows R+w*16..+16), exact row norm
    f16x8 Xh[8], Xl[8];
    float xn;
    {
        float s = 0.f;
#pragma unroll
        for (int kk = 0; kk < 8; ++kk) {
            const float* p = x + (size_t)(R + w * 16 + lr) * D + kk * 32 + q * 8;
            f32x4 a = *reinterpret_cast<const f32x4*>(p);
            f32x4 c = *reinterpret_cast<const f32x4*>(p + 4);
            f16 h0=(f16)a.x,h1=(f16)a.y,h2=(f16)a.z,h3=(f16)a.w;
            f16 h4=(f16)c.x,h5=(f16)c.y,h6=(f16)c.z,h7=(f16)c.w;
            Xh[kk] = (f16x8){h0,h1,h2,h3,h4,h5,h6,h7};
            Xl[kk] = (f16x8){(f16)(a.x-(float)h0),(f16)(a.y-(float)h1),
                             (f16)(a.z-(float)h2),(f16)(a.w-(float)h3),
                             (f16)(c.x-(float)h4),(f16)(c.y-(float)h5),
                             (f16)(c.z-(float)h6),(f16)(c.w-(float)h7)};
            s = fmaf(a.x,a.x,fmaf(a.y,a.y,fmaf(a.z,a.z,fmaf(a.w,a.w,
                fmaf(c.x,c.x,fmaf(c.y,c.y,fmaf(c.z,c.z,fmaf(c.w,c.w,s))))))));
        }
        s += __shfl_xor(s, 16, 64);     // sum 4 q-groups -> full ||x_row||^2
        s += __shfl_xor(s, 32, 64);
        xn = s;
    }

    // stage tile 0 (8 x 1KB wave-instructions per wave; LDS dest wave-uniform base)
#pragma unroll
    for (int i = 0; i < 8; ++i)
        gload_lds16(tab + (w * 8 + i) * 1024 + l * 16, &ebuf[0][(w * 8 + i) * 512]);
    __syncthreads();

    float bV = 3.4e38f;
    int   bI = 0;

    for (int t = 0; t < 32; ++t) {      // 32 e-tiles of 32 embeddings
        const ushort* eb = &ebuf[t & 1][0];
        if (t < 31) {                   // prefetch next tile into other buffer
            const char* gt = tab + (size_t)(t + 1) * 32768;
            ushort* lb = &ebuf[(t + 1) & 1][0];
#pragma unroll
            for (int i = 0; i < 8; ++i)
                gload_lds16(gt + (w * 8 + i) * 1024 + l * 16, lb + (w * 8 + i) * 512);
        }

        // split accumulator chains: accA (Ah*Xh + Ah*Xl), accB (Al*Xh)
        f32x4 accA[2], accB[2];
#pragma unroll
        for (int rf = 0; rf < 2; ++rf) {
            accA[rf] = (f32x4){0.f,0.f,0.f,0.f};
            accB[rf] = (f32x4){0.f,0.f,0.f,0.f};
        }
#pragma unroll
        for (int kk = 0; kk < 8; ++kk) {
            // lane-linear conflict-free ds_read_b128: unit u = kk*4 + spl*2 + rf
            f16x8 Ah0 = *reinterpret_cast<const f16x8*>(eb + (kk*4+0)*512 + l*8);
            f16x8 Ah1 = *reinterpret_cast<const f16x8*>(eb + (kk*4+1)*512 + l*8);
            f16x8 Al0 = *reinterpret_cast<const f16x8*>(eb + (kk*4+2)*512 + l*8);
            f16x8 Al1 = *reinterpret_cast<const f16x8*>(eb + (kk*4+3)*512 + l*8);
            accA[0] = __builtin_amdgcn_mfma_f32_16x16x32_f16(Ah0, Xh[kk], accA[0], 0, 0, 0);
            accA[0] = __builtin_amdgcn_mfma_f32_16x16x32_f16(Ah0, Xl[kk], accA[0], 0, 0, 0);
            accB[0] = __builtin_amdgcn_mfma_f32_16x16x32_f16(Al0, Xh[kk], accB[0], 0, 0, 0);
            accA[1] = __builtin_amdgcn_mfma_f32_16x16x32_f16(Ah1, Xh[kk], accA[1], 0, 0, 0);
            accA[1] = __builtin_amdgcn_mfma_f32_16x16x32_f16(Ah1, Xl[kk], accA[1], 0, 0, 0);
            accB[1] = __builtin_amdgcn_mfma_f32_16x16x32_f16(Al1, Xh[kk], accB[1], 0, 0, 0);
        }
        __syncthreads();                // all eb reads done + prefetch landed

        // fold distances after the barrier (overlaps other waves' barrier exit);
        // emb index ascends with t,rf,i -> strict < = first min
#pragma unroll
        for (int rf = 0; rf < 2; ++rf) {
            f32x4 en4 = *reinterpret_cast<const f32x4*>(&en_s[t * 32 + rf * 16 + q * 4]);
#pragma unroll
            for (int i = 0; i < 4; ++i) {
                float dv = fmaf(-2.f, accA[rf][i] + accB[rf][i], en4[i]);
                int   mi = t * 32 + rf * 16 + q * 4 + i;
                if (dv < bV) { bV = dv; bI = mi; }
            }
        }
    }

    // reduce across q-groups (lanes sharing an x-row), tie -> lower idx
#pragma unroll
    for (int mk = 16; mk <= 32; mk <<= 1) {
        float ov = __shfl_xor(bV, mk, 64);
        int   oi = __shfl_xor(bI, mk, 64);
        if (ov < bV || (ov == bV && oi < bI)) { bV = ov; bI = oi; }
    }
    if (q == 0) {                       // lanes 0..15 hold rows R+w*16+lr
        fidx[w * 16 + lr] = bI;
        outIdx[R + w * 16 + lr] = (float)bI;
        atomicAdd(ws + 1 + bI, 1.0f);
        float ls = bV + xn;
#pragma unroll
        for (int o = 8; o > 0; o >>= 1) ls += __shfl_down(ls, o, 64);
        if (lr == 0) lsum[w] = ls;
    }
    __syncthreads();
    if (tid == 0) atomicAdd(ws, lsum[0] + lsum[1] + lsum[2] + lsum[3]);

    // fused gather: quantized = embedding[idx] (exact fp32), nontemporal store
#pragma unroll
    for (int it = 0; it < 16; ++it) {
        int u = it * 256 + tid;
        int row = u >> 6, c4 = u & 63;  // 64 rows x 64 f32x4 units
        f32x4 v = *reinterpret_cast<const f32x4*>(e + (size_t)fidx[row] * D + c4 * 4);
        __builtin_nontemporal_store(v, reinterpret_cast<f32x4*>(outQ + (size_t)(R + row) * D + c4 * 4));
    }
}

// ---------------- fallback fp32 path (only if ws too small) ----------------
__global__ void enorm_kernel(const float* __restrict__ e, float* __restrict__ enorm) {
    int m = blockIdx.x, l = threadIdx.x;
    const f32x4 v = *reinterpret_cast<const f32x4*>(e + m * D + l * 4);
    float s = fmaf(v.x, v.x, fmaf(v.y, v.y, fmaf(v.z, v.z, v.w * v.w)));
#pragma unroll
    for (int o = 32; o > 0; o >>= 1) s += __shfl_down(s, o, 64);
    if (l == 0) enorm[m] = s;
}

__global__ __launch_bounds__(256, 2) void vq_main_kernel(
    const float* __restrict__ x, const float* __restrict__ e,
    float* __restrict__ outQ, float* __restrict__ outIdx, float* __restrict__ ws) {
    __shared__ f32x4 xs[64][64];
    __shared__ float cval[4][64];
    __shared__ int   cidx[4][64];
    __shared__ int   fidx[64];
    const int tid = threadIdx.x, row0 = blockIdx.x * 64;
#pragma unroll
    for (int it = 0; it < 16; ++it) {
        int f = it * 256 + tid, rr = f >> 6, c4 = f & 63;
        xs[rr][c4 ^ (rr & 7)] = *reinterpret_cast<const f32x4*>(x + (row0 + rr) * D + c4 * 4);
    }
    __syncthreads();
    const int r = tid & 63, c = __builtin_amdgcn_readfirstlane(tid >> 6), sw = r & 7;
    float xnorm = 0.f;
    if (c == 0) {
        f32x4 a = (f32x4){0.f,0.f,0.f,0.f};
        for (int d4 = 0; d4 < 64; ++d4) {
            f32x4 xv = xs[r][d4 ^ sw];
            a.x = fmaf(xv.x, xv.x, a.x); a.y = fmaf(xv.y, xv.y, a.y);
            a.z = fmaf(xv.z, xv.z, a.z); a.w = fmaf(xv.w, xv.w, a.w);
        }
        xnorm = (a.x + a.y) + (a.z + a.w);
    }
    const float* __restrict__ enorm = ws + WS_ENORM_F;
    float bestVal = 3.4e38f; int bestIdx = 0;
    for (int chunk = 0; chunk < M / 32; ++chunk) {
        const int m0 = chunk * 32 + c * 8;
        f32x4 acc[8];
#pragma unroll
        for (int mi = 0; mi < 8; ++mi) acc[mi] = (f32x4){0.f,0.f,0.f,0.f};
#pragma unroll 2
        for (int d4 = 0; d4 < 64; ++d4) {
            const f32x4 xv = xs[r][d4 ^ sw];
#pragma unroll
            for (int mi = 0; mi < 8; ++mi) {
                const f32x4 ev = *reinterpret_cast<const f32x4*>(e + (m0 + mi) * D + d4 * 4);
                acc[mi].x = fmaf(xv.x, ev.x, acc[mi].x); acc[mi].y = fmaf(xv.y, ev.y, acc[mi].y);
                acc[mi].z = fmaf(xv.z, ev.z, acc[mi].z); acc[mi].w = fmaf(xv.w, ev.w, acc[mi].w);
            }
        }
#pragma unroll
        for (int mi = 0; mi < 8; ++mi) {
            float dot = (acc[mi].x + acc[mi].y) + (acc[mi].z + acc[mi].w);
            float val = enorm[m0 + mi] - 2.0f * dot;
            if (val < bestVal) { bestVal = val; bestIdx = m0 + mi; }
        }
    }
    cval[c][r] = bestVal; cidx[c][r] = bestIdx;
    __syncthreads();
    if (c == 0) {
        float bv = bestVal; int bi = bestIdx;
#pragma unroll
        for (int cc = 1; cc < 4; ++cc) {
            float v = cval[cc][r]; int i = cidx[cc][r];
            if (v < bv || (v == bv && i < bi)) { bv = v; bi = i; }
        }
        fidx[r] = bi; outIdx[row0 + r] = (float)bi;
        atomicAdd(ws + 1 + bi, 1.0f);
        float dist = bv + xnorm;
#pragma unroll
        for (int o = 32; o > 0; o >>= 1) dist += __shfl_down(dist, o, 64);
        if (r == 0) atomicAdd(ws, dist);
    }
    __syncthreads();
#pragma unroll
    for (int it = 0; it < 16; ++it) {
        int f = it * 256 + tid, rr = f >> 6, c4 = f & 63;
        *reinterpret_cast<f32x4*>(outQ + (row0 + rr) * D + c4 * 4) =
            *reinterpret_cast<const f32x4*>(e + fidx[rr] * D + c4 * 4);
    }
}

// ---------------- finalize: loss + perplexity ----------------
__global__ void vq_final_kernel(const float* __restrict__ ws,
                                float* __restrict__ outLoss, float* __restrict__ outPpl,
                                float invN, float invND) {
    int t = threadIdx.x;
    float p = ws[1 + t] * invN;
    float term = p * logf(p + 1e-10f);
#pragma unroll
    for (int o = 32; o > 0; o >>= 1) term += __shfl_down(term, o, 64);
    __shared__ float s[16];
    if ((t & 63) == 0) s[t >> 6] = term;
    __syncthreads();
    if (t == 0) {
        float tot = 0.f;
#pragma unroll
        for (int i = 0; i < 16; ++i) tot += s[i];
        *outPpl  = expf(-tot);
        *outLoss = 1.25f * ws[0] * invND;
    }
}

extern "C" void kernel_launch(void* const* d_in, const int* in_sizes, int n_in,
                              void* d_out, int out_size, void* d_ws, size_t ws_size,
                              hipStream_t stream) {
    const float* x = (const float*)d_in[0];
    const float* e = (const float*)d_in[1];
    const int NX = in_sizes[0];     // N*D = 8388608
    const int N  = NX / D;          // 32768

    float* out     = (float*)d_out;
    float* outQ    = out;
    float* outLoss = out + NX;
    float* outIdx  = out + NX + 1;
    float* outPpl  = out + NX + 1 + N;
    float* ws      = (float*)d_ws;

    (void)hipMemsetAsync(d_ws, 0, 4100, stream);    // loss + counts
    if (ws_size >= WS_NEEDED && (N % ROWS) == 0) {
        prep_kernel<<<512, 256, 0, stream>>>(e, ws);
        vq_fused_kernel<<<N / ROWS, 256, 0, stream>>>(x, e, outQ, outIdx, ws);
    } else {
        enorm_kernel<<<M, 64, 0, stream>>>(e, ws + WS_ENORM_F);
        vq_main_kernel<<<N / 64, 256, 0, stream>>>(x, e, outQ, outIdx, ws);
    }
    vq_final_kernel<<<1, 1024, 0, stream>>>(ws, outLoss, outPpl,
                                            1.0f / (float)N, 1.0f / (float)NX);
}